// Round 1
// baseline (65440.076 us; speedup 1.0000x reference)
//
#include <hip/hip_runtime.h>

// ---------------------------------------------------------------------------
// Persistent-kernel seq2seq LSTM for MI355X (gfx950).
// One kernel, 256 blocks (1/CU, forced by ~154KB LDS), 256 threads.
// - Weights live in LDS as split-bf16 (hi+lo), transposed [n][k] for MFMA.
// - Per step: GEMM phase (grid 32 N-groups x 8 K-groups, 16x16x32 bf16 MFMA,
//   3 split terms) -> grid barrier -> pointwise phase (reduce K-partials,
//   sigmoid/tanh, write h as split-bf16 activation planes) -> barrier.
// - Decoder adds fc-partial (fp32 VALU) fused into pointwise, then a softmax
//   phase. y goes back into activation planes for the next step.
// - Grid barrier: two-level atomic tree (8 sub-counters x 32 + master),
//   device-scope atomics + __threadfence for cross-XCD visibility.
// ---------------------------------------------------------------------------

#define TS    384
#define BB    128
#define HIDN  1024
#define DIN   512
#define DOUTN 512
#define G4    4096
#define KTOT  1536
#define KT    192   // K rows per block (8 groups)
#define NT    128   // gate cols per block (32 groups)
#define KH    96    // K per staged half
#define LDA   104   // A LDS stride (shorts): 96 + 8 pad
#define LDB   200   // B LDS stride (shorts): 192 + 8 pad

typedef __attribute__((ext_vector_type(8))) short bf16x8;
typedef __attribute__((ext_vector_type(4))) float f32x4;

// workspace layout (bytes)
#define WS_GP   4096u                              // after 4KB barrier area
#define GP_BYTES (8u*128u*4096u*4u)                // 16MB gate partials
#define WS_FP   (WS_GP + GP_BYTES)
#define FP_BYTES (32u*128u*512u*4u)                // 8MB fc partials
#define WS_AH   (WS_FP + FP_BYTES)
#define AH_BYTES (128u*1536u*2u)                   // act hi plane
#define WS_AL   (WS_AH + AH_BYTES)
#define WS_C    (WS_AL + AH_BYTES)
#define WS_TOTAL (WS_C + 128u*1024u*4u)

__device__ __forceinline__ unsigned short bf16r(float v) {
  unsigned u = __float_as_uint(v);
  u += 0x7FFFu + ((u >> 16) & 1u);          // RNE
  return (unsigned short)(u >> 16);
}
__device__ __forceinline__ float bf2f(unsigned short h) {
  return __uint_as_float(((unsigned)h) << 16);
}
__device__ __forceinline__ void split2(float v, short& hi, short& lo) {
  unsigned short h = bf16r(v);
  float r = v - bf2f(h);                    // exact in fp32
  hi = (short)h;
  lo = (short)bf16r(r);
}
__device__ __forceinline__ float sigm(float v)  { return 1.0f / (1.0f + __expf(-v)); }
__device__ __forceinline__ float tanhfa(float v){ return 1.0f - 2.0f / (__expf(2.0f*v) + 1.0f); }

// ---- two-level grid barrier -------------------------------------------------
__device__ __forceinline__ void gbar(char* ws, int b, unsigned& epoch, bool& dead) {
  __syncthreads();
  if (threadIdx.x == 0) {
    ++epoch;
    __threadfence();                                       // flush block's writes device-wide
    unsigned* gen = (unsigned*)ws;                          // ws+0
    unsigned* sub = (unsigned*)(ws + 256u * (1u + (b & 7))); // 8 sub counters
    unsigned* mas = (unsigned*)(ws + 256u * 9u);
    unsigned old = __hip_atomic_fetch_add(sub, 1u, __ATOMIC_ACQ_REL, __HIP_MEMORY_SCOPE_AGENT);
    bool released_here = false;
    if (old == 31u) {                                       // last of sub-group
      unsigned om = __hip_atomic_fetch_add(mas, 1u, __ATOMIC_ACQ_REL, __HIP_MEMORY_SCOPE_AGENT);
      if (om == 7u) {                                       // global last
        #pragma unroll
        for (int i = 0; i < 8; ++i)
          __hip_atomic_store((unsigned*)(ws + 256u*(1u+i)), 0u, __ATOMIC_RELAXED, __HIP_MEMORY_SCOPE_AGENT);
        __hip_atomic_store(mas, 0u, __ATOMIC_RELAXED, __HIP_MEMORY_SCOPE_AGENT);
        __hip_atomic_store(gen, epoch, __ATOMIC_RELEASE, __HIP_MEMORY_SCOPE_AGENT);
        released_here = true;
      }
    }
    if (!released_here && !dead) {
      unsigned spins = 0;
      while (__hip_atomic_load(gen, __ATOMIC_RELAXED, __HIP_MEMORY_SCOPE_AGENT) < epoch) {
        __builtin_amdgcn_s_sleep(2);
        if (++spins > (1u << 22)) { dead = true; break; }   // anti-hang safety
      }
    }
    __threadfence();                                       // acquire side
  }
  __syncthreads();
}

// ---- per-step GEMM: [128 x KT] @ [KT x NT] split-bf16 MFMA ------------------
__device__ __forceinline__ void gemm_step(
    const short* __restrict__ actH, const short* __restrict__ actL,
    float* __restrict__ gp, int kg, int ng, int wv, int lane, int tid,
    short* sAh, short* sAl, const short* sBh, const short* sBl)
{
  f32x4 acc[2][8];
  #pragma unroll
  for (int m = 0; m < 2; ++m)
    #pragma unroll
    for (int n = 0; n < 8; ++n) {
      acc[m][n][0] = 0.f; acc[m][n][1] = 0.f; acc[m][n][2] = 0.f; acc[m][n][3] = 0.f;
    }

  #pragma unroll
  for (int half = 0; half < 2; ++half) {
    // stage A half: 128 rows x 96 k (hi+lo), 12 chunks of 8 bf16 per row
    #pragma unroll
    for (int i = 0; i < 6; ++i) {
      int flat = i * 256 + tid;               // 0..1535
      int r = flat / 12, ch = flat - r * 12;
      int gk = kg * KT + half * KH + ch * 8;
      *(bf16x8*)&sAh[r * LDA + ch * 8] = *(const bf16x8*)&actH[(size_t)r * KTOT + gk];
      *(bf16x8*)&sAl[r * LDA + ch * 8] = *(const bf16x8*)&actL[(size_t)r * KTOT + gk];
    }
    __syncthreads();
    const int lmm = lane & 15;
    #pragma unroll
    for (int ks = 0; ks < 3; ++ks) {
      const int lk = ((lane >> 4) << 3) + ks * 32;   // k within half
      bf16x8 ah[2], al[2], bh[8], bl[8];
      #pragma unroll
      for (int m = 0; m < 2; ++m) {
        const int row = wv * 32 + m * 16 + lmm;
        ah[m] = *(const bf16x8*)&sAh[row * LDA + lk];
        al[m] = *(const bf16x8*)&sAl[row * LDA + lk];
      }
      const int kb = half * KH + lk;
      #pragma unroll
      for (int n = 0; n < 8; ++n) {
        const int cl = n * 16 + lmm;
        bh[n] = *(const bf16x8*)&sBh[cl * LDB + kb];
        bl[n] = *(const bf16x8*)&sBl[cl * LDB + kb];
      }
      // term 1: Ah*Bh  (interleave over 16 accs -> no dependency stalls)
      #pragma unroll
      for (int n = 0; n < 8; ++n)
        #pragma unroll
        for (int m = 0; m < 2; ++m)
          acc[m][n] = __builtin_amdgcn_mfma_f32_16x16x32_bf16(ah[m], bh[n], acc[m][n], 0, 0, 0);
      // term 2: Ah*Bl
      #pragma unroll
      for (int n = 0; n < 8; ++n)
        #pragma unroll
        for (int m = 0; m < 2; ++m)
          acc[m][n] = __builtin_amdgcn_mfma_f32_16x16x32_bf16(ah[m], bl[n], acc[m][n], 0, 0, 0);
      // term 3: Al*Bh
      #pragma unroll
      for (int n = 0; n < 8; ++n)
        #pragma unroll
        for (int m = 0; m < 2; ++m)
          acc[m][n] = __builtin_amdgcn_mfma_f32_16x16x32_bf16(al[m], bh[n], acc[m][n], 0, 0, 0);
    }
    __syncthreads();
  }
  // store K-partials
  float* gpk = gp + (size_t)kg * BB * G4;
  const int lmm = lane & 15, lq = (lane >> 4) << 2;
  #pragma unroll
  for (int m = 0; m < 2; ++m)
    #pragma unroll
    for (int n = 0; n < 8; ++n)
      #pragma unroll
      for (int j = 0; j < 4; ++j) {
        const int row = wv * 32 + m * 16 + lq + j;       // C/D: row=(l>>4)*4+reg
        const int col = ng * NT + n * 16 + lmm;          //      col=l&15
        gpk[(size_t)row * G4 + col] = acc[m][n][j];
      }
}

__device__ __forceinline__ void load_weights(
    const float* __restrict__ Wx, const float* __restrict__ Wh,
    int kg, int ng, int tid, short* sBh, short* sBl)
{
  #pragma unroll 1
  for (int i = 0; i < 96; ++i) {
    int flat = i * 256 + tid;                 // [kl 192][nl 128]
    int kl = flat >> 7, nl = flat & 127;
    int K = kg * KT + kl, col = ng * NT + nl;
    float w = (K < DIN) ? Wx[(size_t)K * G4 + col] : Wh[(size_t)(K - DIN) * G4 + col];
    short hi, lo; split2(w, hi, lo);
    sBh[nl * LDB + kl] = hi;                  // stored transposed: [n][k]
    sBl[nl * LDB + kl] = lo;
  }
}

__global__ void __launch_bounds__(256, 1)
lstm_persist(const float* __restrict__ x, const float* __restrict__ h0p,
             const float* __restrict__ c0p, const float* __restrict__ eWx,
             const float* __restrict__ eWh, const float* __restrict__ eb,
             const float* __restrict__ dWx, const float* __restrict__ dWh,
             const float* __restrict__ db, const float* __restrict__ fcW,
             const float* __restrict__ fcb, float* __restrict__ out,
             char* __restrict__ ws)
{
  __shared__ __align__(16) short sBh[NT * LDB];   // 50KB
  __shared__ __align__(16) short sBl[NT * LDB];   // 50KB
  __shared__ __align__(16) short sAh[BB * LDA];   // 26KB
  __shared__ __align__(16) short sAl[BB * LDA];   // 26KB
  __shared__ __align__(16) float sH[16 * 32];     // 2KB
  __shared__ float sRed[8];

  const int b = blockIdx.x, tid = threadIdx.x;
  const int wv = tid >> 6, lane = tid & 63;
  const int kg = b & 7, ng = b >> 3;

  float* gp   = (float*)(ws + WS_GP);
  float* fp   = (float*)(ws + WS_FP);
  short* actH = (short*)(ws + WS_AH);
  short* actL = (short*)(ws + WS_AL);
  float* cst  = (float*)(ws + WS_C);

  unsigned epoch = 0;
  bool dead = false;

  // ---- init: encoder weights -> LDS; act planes = [x0 | h0]; c = c0 ----
  load_weights(eWx, eWh, kg, ng, tid, sBh, sBl);
  #pragma unroll 1
  for (int i = 0; i < 3; ++i) {
    int flat = b * 256 + tid + i * 65536;     // [r 128][k 1536]
    int r = flat / KTOT, k = flat - r * KTOT;
    float v = (k < DIN) ? x[(size_t)r * DIN + k] : h0p[(size_t)r * HIDN + (k - DIN)];
    short hi, lo; split2(v, hi, lo);
    actH[flat] = hi;
    actL[flat] = lo;
  }
  {
    int f2 = b * 256 + tid;
    cst[f2] = c0p[f2];
    cst[f2 + 65536] = c0p[f2 + 65536];
  }
  gbar(ws, b, epoch, dead);

  // =========================== ENCODER ===========================
  #pragma unroll 1
  for (int step = 0; step < TS; ++step) {
    gemm_step(actH, actL, gp, kg, ng, wv, lane, tid, sAh, sAl, sBh, sBl);
    gbar(ws, b, epoch, dead);
    // pointwise: reduce partials + bias, LSTM cell, write h planes
    {
      const int rg = b >> 5, ug = b & 31;
      const int rl = tid >> 4, u2 = (tid & 15) << 1;
      const int r = rg * 16 + rl, u = ug * 32 + u2;
      float gt[4][2];
      #pragma unroll
      for (int q = 0; q < 4; ++q) {
        const int col = q * HIDN + u;
        float2 sv = *(const float2*)(eb + col);
        #pragma unroll
        for (int k = 0; k < 8; ++k) {
          float2 pv = *(const float2*)(gp + ((size_t)k * BB + r) * G4 + col);
          sv.x += pv.x; sv.y += pv.y;
        }
        gt[q][0] = sv.x; gt[q][1] = sv.y;
      }
      float2 cv = *(const float2*)&cst[(size_t)r * HIDN + u];
      float cn0 = sigm(gt[1][0]) * cv.x + sigm(gt[0][0]) * tanhfa(gt[2][0]);
      float cn1 = sigm(gt[1][1]) * cv.y + sigm(gt[0][1]) * tanhfa(gt[2][1]);
      *(float2*)&cst[(size_t)r * HIDN + u] = make_float2(cn0, cn1);
      float hv0 = sigm(gt[3][0]) * tanhfa(cn0);
      float hv1 = sigm(gt[3][1]) * tanhfa(cn1);
      short h0s, l0s, h1s, l1s;
      split2(hv0, h0s, l0s); split2(hv1, h1s, l1s);
      *(short2*)&actH[(size_t)r * KTOT + DIN + u] = make_short2(h0s, h1s);
      *(short2*)&actL[(size_t)r * KTOT + DIN + u] = make_short2(l0s, l1s);
      if (step + 1 < TS) {                    // convert x_{t+1} into act planes
        int flat = b * 256 + tid;             // exactly 128*512 elements
        int rr = flat >> 9, d = flat & 511;
        float v = x[((size_t)(step + 1) * BB + rr) * DIN + d];
        short hi, lo; split2(v, hi, lo);
        actH[(size_t)rr * KTOT + d] = hi;
        actL[(size_t)rr * KTOT + d] = lo;
      }
    }
    gbar(ws, b, epoch, dead);
  }

  // ---- switch to decoder: dec weights, y0 = 0, c = 0 (h planes keep h_enc)
  load_weights(dWx, dWh, kg, ng, tid, sBh, sBl);
  {
    int flat = b * 256 + tid;
    int rr = flat >> 9, d = flat & 511;
    actH[(size_t)rr * KTOT + d] = 0;
    actL[(size_t)rr * KTOT + d] = 0;
    cst[flat] = 0.0f;
    cst[flat + 65536] = 0.0f;
  }
  gbar(ws, b, epoch, dead);

  // =========================== DECODER ===========================
  #pragma unroll 1
  for (int step = 0; step < TS; ++step) {
    gemm_step(actH, actL, gp, kg, ng, wv, lane, tid, sAh, sAl, sBh, sBl);
    gbar(ws, b, epoch, dead);
    // P2: pointwise + fc partial over this block's 32-unit slice
    {
      const int rg = b >> 5, ug = b & 31;
      const int rl = tid >> 4, u2 = (tid & 15) << 1;
      const int r = rg * 16 + rl, u = ug * 32 + u2;
      float gt[4][2];
      #pragma unroll
      for (int q = 0; q < 4; ++q) {
        const int col = q * HIDN + u;
        float2 sv = *(const float2*)(db + col);
        #pragma unroll
        for (int k = 0; k < 8; ++k) {
          float2 pv = *(const float2*)(gp + ((size_t)k * BB + r) * G4 + col);
          sv.x += pv.x; sv.y += pv.y;
        }
        gt[q][0] = sv.x; gt[q][1] = sv.y;
      }
      float2 cv = *(const float2*)&cst[(size_t)r * HIDN + u];
      float cn0 = sigm(gt[1][0]) * cv.x + sigm(gt[0][0]) * tanhfa(gt[2][0]);
      float cn1 = sigm(gt[1][1]) * cv.y + sigm(gt[0][1]) * tanhfa(gt[2][1]);
      *(float2*)&cst[(size_t)r * HIDN + u] = make_float2(cn0, cn1);
      float hv0 = sigm(gt[3][0]) * tanhfa(cn0);
      float hv1 = sigm(gt[3][1]) * tanhfa(cn1);
      short h0s, l0s, h1s, l1s;
      split2(hv0, h0s, l0s); split2(hv1, h1s, l1s);
      *(short2*)&actH[(size_t)r * KTOT + DIN + u] = make_short2(h0s, h1s);
      *(short2*)&actL[(size_t)r * KTOT + DIN + u] = make_short2(l0s, l1s);
      sH[rl * 32 + u2]     = hv0;
      sH[rl * 32 + u2 + 1] = hv1;
      __syncthreads();
      // fc partial: this thread owns output cols {2*tid, 2*tid+1}
      float a0[16], a1[16];
      #pragma unroll
      for (int rr = 0; rr < 16; ++rr) { a0[rr] = 0.f; a1[rr] = 0.f; }
      const float2* Wf = (const float2*)fcW;   // [1024][256] float2
      #pragma unroll
      for (int u4 = 0; u4 < 8; ++u4) {
        float2 w0 = Wf[((size_t)(ug * 32 + u4 * 4 + 0)) * 256 + tid];
        float2 w1 = Wf[((size_t)(ug * 32 + u4 * 4 + 1)) * 256 + tid];
        float2 w2 = Wf[((size_t)(ug * 32 + u4 * 4 + 2)) * 256 + tid];
        float2 w3 = Wf[((size_t)(ug * 32 + u4 * 4 + 3)) * 256 + tid];
        #pragma unroll
        for (int rr = 0; rr < 16; ++rr) {
          float4 hq = *(const float4*)&sH[rr * 32 + u4 * 4];
          a0[rr] += hq.x * w0.x + hq.y * w1.x + hq.z * w2.x + hq.w * w3.x;
          a1[rr] += hq.x * w0.y + hq.y * w1.y + hq.z * w2.y + hq.w * w3.y;
        }
      }
      float* fpp = fp + (size_t)ug * BB * DOUTN;
      #pragma unroll
      for (int rr = 0; rr < 16; ++rr)
        *(float2*)&fpp[(size_t)(rg * 16 + rr) * DOUTN + (tid << 1)] = make_float2(a0[rr], a1[rr]);
    }
    gbar(ws, b, epoch, dead);
    // P3: softmax (one block per batch row), write y to out + act planes
    if (b < BB) {
      const int c = tid << 1;
      float v0 = fcb[c], v1 = fcb[c + 1];
      #pragma unroll
      for (int uu = 0; uu < 32; ++uu) {
        float2 pv = *(const float2*)&fp[((size_t)uu * BB + b) * DOUTN + c];
        v0 += pv.x; v1 += pv.y;
      }
      float m = fmaxf(v0, v1);
      #pragma unroll
      for (int o = 32; o > 0; o >>= 1) m = fmaxf(m, __shfl_xor(m, o));
      if (lane == 0) sRed[wv] = m;
      __syncthreads();
      m = fmaxf(fmaxf(sRed[0], sRed[1]), fmaxf(sRed[2], sRed[3]));
      float e0 = __expf(v0 - m), e1 = __expf(v1 - m);
      float s = e0 + e1;
      #pragma unroll
      for (int o = 32; o > 0; o >>= 1) s += __shfl_xor(s, o);
      __syncthreads();
      if (lane == 0) sRed[4 + wv] = s;
      __syncthreads();
      s = (sRed[4] + sRed[5]) + (sRed[6] + sRed[7]);
      float y0 = e0 / s, y1 = e1 / s;
      *(float2*)&out[((size_t)step * BB + b) * DOUTN + c] = make_float2(y0, y1);
      short hi0, lo0, hi1, lo1;
      split2(y0, hi0, lo0); split2(y1, hi1, lo1);
      *(short2*)&actH[(size_t)b * KTOT + c] = make_short2(hi0, hi1);
      *(short2*)&actL[(size_t)b * KTOT + c] = make_short2(lo0, lo1);
    }
    gbar(ws, b, epoch, dead);
  }
}

extern "C" void kernel_launch(void* const* d_in, const int* in_sizes, int n_in,
                              void* d_out, int out_size, void* d_ws, size_t ws_size,
                              hipStream_t stream) {
  const float* x   = (const float*)d_in[0];
  const float* h0  = (const float*)d_in[1];
  const float* c0  = (const float*)d_in[2];
  const float* eWx = (const float*)d_in[3];
  const float* eWh = (const float*)d_in[4];
  const float* eb  = (const float*)d_in[5];
  const float* dWx = (const float*)d_in[6];
  const float* dWh = (const float*)d_in[7];
  const float* db  = (const float*)d_in[8];
  const float* fcW = (const float*)d_in[9];
  const float* fcb = (const float*)d_in[10];
  float* out = (float*)d_out;

  if (ws_size < (size_t)WS_TOTAL) {
    // distinctive failure signature (NaN fill) instead of memory corruption
    hipMemsetAsync(d_out, 0xFF, (size_t)out_size * sizeof(float), stream);
    return;
  }
  hipMemsetAsync(d_ws, 0, 4096, stream);   // barrier counters/gen
  hipLaunchKernelGGL(lstm_persist, dim3(256), dim3(256), 0, stream,
                     x, h0, c0, eWx, eWh, eb, dWx, dWh, db, fcW, fcb, out,
                     (char*)d_ws);
}

// Round 2
// 25432.713 us; speedup vs baseline: 2.5731x; 2.5731x over previous
//
#include <hip/hip_runtime.h>

// ---------------------------------------------------------------------------
// Persistent seq2seq LSTM, v2: zero-partials decomposition.
// 256 blocks (1/CU) x 512 threads (8 waves). Block p owns 4 units (16 gate
// cols: q*1024 + p*4 + u), FULL K=1536 -> gates complete in-block; c in regs.
// Activations ([x|h] split-bf16 hi/lo) live in ws in MFMA-fragment order:
//   chunk g=(kb*8+mt)*64+lane holds 8 bf16 = A-frag (row=mt*16+(lane&15),
//   k=kb*32+(lane>>4)*8). Writers pre-swizzle; GEMM loads 16B/lane stride-1.
// Cross-block data written ONLY via agent write-through atomics -> barrier
// release = vmcnt(0) (no L2 writeback); acquire = fence(acquire, agent).
// Encoder: 1 barrier/step. Decoder: chain counters (pointwise->fc->softmax)
// + 1 barrier/step. fc uses MFMA with fcW split-bf16 frags in LDS (loaded
// once). 6 accumulators break MFMA dep chains.
// ---------------------------------------------------------------------------

#define TS 384

typedef __attribute__((ext_vector_type(8))) short bf16x8;
typedef __attribute__((ext_vector_type(4))) float f32x4;

#define ACT_PLANE 393216u                      // 24576 chunks * 16B
#define WS_ACT 4096u                           // [buf0H, buf0L, buf1H, buf1L]
#define WS_FP  (WS_ACT + 4u*ACT_PLANE)         // fc partials 4*128*512*4 = 1MB
#define WS_TOTAL (WS_FP + 1048576u)

__device__ __forceinline__ unsigned short bf16r(float v) {
  unsigned u = __float_as_uint(v);
  u += 0x7FFFu + ((u >> 16) & 1u);
  return (unsigned short)(u >> 16);
}
__device__ __forceinline__ float bf2f(unsigned short h) {
  return __uint_as_float(((unsigned)h) << 16);
}
__device__ __forceinline__ void split2(float v, short& hi, short& lo) {
  unsigned short h = bf16r(v);
  float r = v - bf2f(h);
  hi = (short)h; lo = (short)bf16r(r);
}
__device__ __forceinline__ float sigm(float v)  { return 1.0f / (1.0f + __expf(-v)); }
__device__ __forceinline__ float tanhfa(float v){ return 1.0f - 2.0f / (__expf(2.0f*v) + 1.0f); }

__device__ __forceinline__ void st_u64(short* p, unsigned long long v) {
  __hip_atomic_store((unsigned long long*)p, v, __ATOMIC_RELAXED, __HIP_MEMORY_SCOPE_AGENT);
}
__device__ __forceinline__ void st_f32(float* p, float v) {
  __hip_atomic_store(p, v, __ATOMIC_RELAXED, __HIP_MEMORY_SCOPE_AGENT);
}
__device__ __forceinline__ float ld_f32(const float* p) {
  return __hip_atomic_load(p, __ATOMIC_RELAXED, __HIP_MEMORY_SCOPE_AGENT);
}

// element (row,k) -> short offset in a fragment-ordered plane
__device__ __forceinline__ int elem_off(int row, int k) {
  int kb = k >> 5, mt = row >> 4, lane = (((k >> 3) & 3) << 4) | (row & 15);
  return (((kb * 8 + mt) * 64) + lane) * 8 + (k & 7);
}

// ---- sync primitives --------------------------------------------------------
__device__ __forceinline__ void step_barrier(unsigned* cnt, unsigned& bar_no, int* sDead) {
  asm volatile("s_waitcnt vmcnt(0)" ::: "memory");   // every wave drains its WT stores
  __syncthreads();
  ++bar_no;
  if (threadIdx.x == 0) {
    __hip_atomic_fetch_add(cnt, 1u, __ATOMIC_RELAXED, __HIP_MEMORY_SCOPE_AGENT);
    unsigned target = bar_no * 256u, spins = 0;
    while (__hip_atomic_load(cnt, __ATOMIC_RELAXED, __HIP_MEMORY_SCOPE_AGENT) < target) {
      __builtin_amdgcn_s_sleep(2);
      if (++spins > (1u << 21)) { *sDead = 1; break; }
    }
    __builtin_amdgcn_fence(__ATOMIC_ACQUIRE, "agent");  // inv L1/L2 (no wb needed)
  }
  __syncthreads();
}
__device__ __forceinline__ void chain_add(unsigned* cnt) {
  asm volatile("s_waitcnt vmcnt(0)" ::: "memory");
  __syncthreads();
  if (threadIdx.x == 0)
    __hip_atomic_fetch_add(cnt, 1u, __ATOMIC_RELAXED, __HIP_MEMORY_SCOPE_AGENT);
}
__device__ __forceinline__ void chain_wait(unsigned* cnt, unsigned target, bool fence, int* sDead) {
  if (threadIdx.x == 0) {
    unsigned spins = 0;
    while (__hip_atomic_load(cnt, __ATOMIC_RELAXED, __HIP_MEMORY_SCOPE_AGENT) < target) {
      __builtin_amdgcn_s_sleep(2);
      if (++spins > (1u << 21)) { *sDead = 1; break; }
    }
    if (fence) __builtin_amdgcn_fence(__ATOMIC_ACQUIRE, "agent");
  }
  __syncthreads();
}

// ---- weight loaders (once per phase) ---------------------------------------
__device__ void load_gate_weights(const float* __restrict__ Wx, const float* __restrict__ Wh,
                                  int p, short* sBh, short* sBl) {
  for (int idx = threadIdx.x; idx < 24576; idx += 512) {
    int j = idx & 7, l = (idx >> 3) & 63, kb = idx >> 9;
    int k = kb * 32 + ((l >> 4) << 3) + j;
    int c = l & 15;
    int gcol = (c >> 2) * 1024 + p * 4 + (c & 3);   // q=c>>2, u=c&3
    float wv = (k < 512) ? Wx[(size_t)k * 4096 + gcol]
                         : Wh[(size_t)(k - 512) * 4096 + gcol];
    short hi, lo; split2(wv, hi, lo);
    sBh[idx] = hi; sBl[idx] = lo;
  }
}
__device__ void load_fc_weights(const float* __restrict__ fcW, int kg, int cg,
                                short* sFh, short* sFl) {
  for (int idx = threadIdx.x; idx < 4096; idx += 512) {
    int j = idx & 7, l = (idx >> 3) & 63, kb = idx >> 9;
    int unit = kg * 256 + kb * 32 + ((l >> 4) << 3) + j;
    int col = cg * 16 + (l & 15);
    short hi, lo; split2(fcW[(size_t)unit * 512 + col], hi, lo);
    sFh[idx] = hi; sFl[idx] = lo;
  }
}

// ---- main gate GEMM: [128 x 1536] @ [1536 x 16], 3-term split-bf16 ---------
__device__ __forceinline__ void gate_gemm(
    const bf16x8* __restrict__ AH, const bf16x8* __restrict__ AL,
    const short* __restrict__ sBh, const short* __restrict__ sBl,
    int w, int l, float* __restrict__ LDSgate)
{
  const bf16x8* BH = (const bf16x8*)sBh;
  const bf16x8* BL = (const bf16x8*)sBl;
  f32x4 z = {0.f, 0.f, 0.f, 0.f};
  f32x4 a0 = z, a1 = z, a2 = z, a3 = z, a4 = z, a5 = z;
  #pragma unroll 4
  for (int kb = 0; kb < 48; kb += 2) {
    bf16x8 ah0 = AH[(kb * 8 + w) * 64 + l];
    bf16x8 al0 = AL[(kb * 8 + w) * 64 + l];
    bf16x8 bh0 = BH[kb * 64 + l];
    bf16x8 bl0 = BL[kb * 64 + l];
    bf16x8 ah1 = AH[((kb + 1) * 8 + w) * 64 + l];
    bf16x8 al1 = AL[((kb + 1) * 8 + w) * 64 + l];
    bf16x8 bh1 = BH[(kb + 1) * 64 + l];
    bf16x8 bl1 = BL[(kb + 1) * 64 + l];
    a0 = __builtin_amdgcn_mfma_f32_16x16x32_bf16(ah0, bh0, a0, 0, 0, 0);
    a1 = __builtin_amdgcn_mfma_f32_16x16x32_bf16(ah0, bl0, a1, 0, 0, 0);
    a2 = __builtin_amdgcn_mfma_f32_16x16x32_bf16(al0, bh0, a2, 0, 0, 0);
    a3 = __builtin_amdgcn_mfma_f32_16x16x32_bf16(ah1, bh1, a3, 0, 0, 0);
    a4 = __builtin_amdgcn_mfma_f32_16x16x32_bf16(ah1, bl1, a4, 0, 0, 0);
    a5 = __builtin_amdgcn_mfma_f32_16x16x32_bf16(al1, bh1, a5, 0, 0, 0);
  }
  f32x4 s = (a0 + a3) + ((a1 + a4) + (a2 + a5));
  const int col = l & 15, r0 = w * 16 + ((l >> 4) << 2);
  #pragma unroll
  for (int j = 0; j < 4; ++j) LDSgate[(r0 + j) * 17 + col] = s[j];
}

// ---- x / y / h0 conversions into fragment-ordered planes -------------------
__device__ __forceinline__ void conv_x(const float* __restrict__ xsrc,
                                       short* dstH, short* dstL, int p, int t) {
  if (t < 32) {
    int g = p * 32 + t;                       // chunk id < 8192 (k < 512)
    int l = g & 63, mt = (g >> 6) & 7, kb = g >> 9;
    int row = mt * 16 + (l & 15), k = kb * 32 + ((l >> 4) << 3);
    const float* xs = xsrc + (size_t)row * 512 + k;
    unsigned long long h64[2] = {0, 0}, l64[2] = {0, 0};
    #pragma unroll
    for (int j = 0; j < 8; ++j) {
      short hi, lo; split2(xs[j], hi, lo);
      h64[j >> 2] |= (unsigned long long)(unsigned short)hi << ((j & 3) * 16);
      l64[j >> 2] |= (unsigned long long)(unsigned short)lo << ((j & 3) * 16);
    }
    int off = g * 8;
    st_u64(dstH + off, h64[0]); st_u64(dstH + off + 4, h64[1]);
    st_u64(dstL + off, l64[0]); st_u64(dstL + off + 4, l64[1]);
  }
}

__global__ void __launch_bounds__(512)
lstm2(const float* __restrict__ x, const float* __restrict__ h0p,
      const float* __restrict__ c0p, const float* __restrict__ eWx,
      const float* __restrict__ eWh, const float* __restrict__ eb,
      const float* __restrict__ dWx, const float* __restrict__ dWh,
      const float* __restrict__ db, const float* __restrict__ fcW,
      const float* __restrict__ fcb, float* __restrict__ out,
      char* __restrict__ ws)
{
  __shared__ __align__(16) short sBh[24576], sBl[24576];   // 96 KB gate weights
  __shared__ __align__(16) short sFh[4096], sFl[4096];     // 16 KB fc weights
  __shared__ float LDSgate[128 * 17];                      // 8.7 KB
  __shared__ unsigned hsplit[512];
  __shared__ float ybuf[512];
  __shared__ float red[16];
  __shared__ int sDead;

  const int p = blockIdx.x, t = threadIdx.x;
  const int w = t >> 6, l = t & 63;
  if (t == 0) sDead = 0;

  unsigned* cnt_bar = (unsigned*)ws;
  unsigned* cnt_fc  = (unsigned*)(ws + 1024);
  float* fp = (float*)(ws + WS_FP);
  short* planeH[2] = { (short*)(ws + WS_ACT),                  (short*)(ws + WS_ACT + 2*ACT_PLANE) };
  short* planeL[2] = { (short*)(ws + WS_ACT + ACT_PLANE),      (short*)(ws + WS_ACT + 3*ACT_PLANE) };

  const int row_pw = t & 127, u_pw = t >> 7;     // pointwise cell: (row, unit u)
  unsigned bar_no = 0;

  // ================= init =================
  load_gate_weights(eWx, eWh, p, sBh, sBl);
  conv_x(x, planeH[0], planeL[0], p, t);
  if (t < 64) {                                  // h0 -> buf0 h-region
    int g = 8192 + p * 64 + t;
    int ll = g & 63, mt = (g >> 6) & 7, kb = g >> 9;
    int row = mt * 16 + (ll & 15), k = kb * 32 + ((ll >> 4) << 3);
    const float* hs = h0p + (size_t)row * 1024 + (k - 512);
    unsigned long long h64[2] = {0, 0}, l64[2] = {0, 0};
    #pragma unroll
    for (int j = 0; j < 8; ++j) {
      short hi, lo; split2(hs[j], hi, lo);
      h64[j >> 2] |= (unsigned long long)(unsigned short)hi << ((j & 3) * 16);
      l64[j >> 2] |= (unsigned long long)(unsigned short)lo << ((j & 3) * 16);
    }
    int off = g * 8;
    st_u64(planeH[0] + off, h64[0]); st_u64(planeH[0] + off + 4, h64[1]);
    st_u64(planeL[0] + off, l64[0]); st_u64(planeL[0] + off + 4, l64[1]);
  }
  float creg = c0p[(size_t)row_pw * 1024 + p * 4 + u_pw];
  float bq[4];
  #pragma unroll
  for (int q = 0; q < 4; ++q) bq[q] = eb[q * 1024 + p * 4 + u_pw];
  step_barrier(cnt_bar, bar_no, &sDead);
  if (sDead) return;

  // ================= encoder =================
  for (int st = 0; st < TS; ++st) {
    int rb = st & 1, wb = rb ^ 1;
    gate_gemm((const bf16x8*)planeH[rb], (const bf16x8*)planeL[rb], sBh, sBl, w, l, LDSgate);
    __syncthreads();
    {
      float g0 = LDSgate[row_pw * 17 + 0  + u_pw] + bq[0];
      float g1 = LDSgate[row_pw * 17 + 4  + u_pw] + bq[1];
      float g2 = LDSgate[row_pw * 17 + 8  + u_pw] + bq[2];
      float g3 = LDSgate[row_pw * 17 + 12 + u_pw] + bq[3];
      creg = sigm(g1) * creg + sigm(g0) * tanhfa(g2);
      float h = sigm(g3) * tanhfa(creg);
      short hi, lo; split2(h, hi, lo);
      hsplit[u_pw * 128 + row_pw] = ((unsigned)(unsigned short)hi << 16) | (unsigned short)lo;
    }
    if (st + 1 < TS) conv_x(x + (size_t)(st + 1) * 128 * 512, planeH[wb], planeL[wb], p, t);
    __syncthreads();
    if (t < 128) {                               // pack+store h slice (4 units)
      int r = t;
      unsigned w0 = hsplit[r], w1 = hsplit[128 + r], w2 = hsplit[256 + r], w3 = hsplit[384 + r];
      unsigned long long hi64 = (unsigned long long)(w0 >> 16)
        | ((unsigned long long)(w1 >> 16) << 16)
        | ((unsigned long long)(w2 >> 16) << 32)
        | ((unsigned long long)(w3 >> 16) << 48);
      unsigned long long lo64 = (unsigned long long)(w0 & 0xFFFFu)
        | ((unsigned long long)(w1 & 0xFFFFu) << 16)
        | ((unsigned long long)(w2 & 0xFFFFu) << 32)
        | ((unsigned long long)(w3 & 0xFFFFu) << 48);
      int off = elem_off(r, 512 + p * 4);
      st_u64(planeH[wb] + off, hi64);
      st_u64(planeL[wb] + off, lo64);
    }
    step_barrier(cnt_bar, bar_no, &sDead);
    if (sDead) return;
  }

  // ================= switch to decoder =================
  load_gate_weights(dWx, dWh, p, sBh, sBl);
  if (p < 128) load_fc_weights(fcW, p >> 5, p & 31, sFh, sFl);
  if (t < 32) {                                  // zero y region of buf0
    int off = (p * 32 + t) * 8;
    st_u64(planeH[0] + off, 0ull); st_u64(planeH[0] + off + 4, 0ull);
    st_u64(planeL[0] + off, 0ull); st_u64(planeL[0] + off + 4, 0ull);
  }
  creg = 0.0f;
  #pragma unroll
  for (int q = 0; q < 4; ++q) bq[q] = db[q * 1024 + p * 4 + u_pw];
  float fcb_r = fcb[t];
  step_barrier(cnt_bar, bar_no, &sDead);
  if (sDead) return;

  // ================= decoder =================
  for (int st = 0; st < TS; ++st) {
    int rb = st & 1, wb = rb ^ 1;
    gate_gemm((const bf16x8*)planeH[rb], (const bf16x8*)planeL[rb], sBh, sBl, w, l, LDSgate);
    __syncthreads();
    {
      float g0 = LDSgate[row_pw * 17 + 0  + u_pw] + bq[0];
      float g1 = LDSgate[row_pw * 17 + 4  + u_pw] + bq[1];
      float g2 = LDSgate[row_pw * 17 + 8  + u_pw] + bq[2];
      float g3 = LDSgate[row_pw * 17 + 12 + u_pw] + bq[3];
      creg = sigm(g1) * creg + sigm(g0) * tanhfa(g2);
      float h = sigm(g3) * tanhfa(creg);
      short hi, lo; split2(h, hi, lo);
      hsplit[u_pw * 128 + row_pw] = ((unsigned)(unsigned short)hi << 16) | (unsigned short)lo;
    }
    __syncthreads();
    if (t < 128) {
      int r = t;
      unsigned w0 = hsplit[r], w1 = hsplit[128 + r], w2 = hsplit[256 + r], w3 = hsplit[384 + r];
      unsigned long long hi64 = (unsigned long long)(w0 >> 16)
        | ((unsigned long long)(w1 >> 16) << 16)
        | ((unsigned long long)(w2 >> 16) << 32)
        | ((unsigned long long)(w3 >> 16) << 48);
      unsigned long long lo64 = (unsigned long long)(w0 & 0xFFFFu)
        | ((unsigned long long)(w1 & 0xFFFFu) << 16)
        | ((unsigned long long)(w2 & 0xFFFFu) << 32)
        | ((unsigned long long)(w3 & 0xFFFFu) << 48);
      int off = elem_off(r, 512 + p * 4);
      st_u64(planeH[wb] + off, hi64);
      st_u64(planeL[wb] + off, lo64);
    }
    chain_add((unsigned*)(ws + 256 + (p >> 6) * 64));   // h slice done
    if (p < 128) {
      int kg = p >> 5, cg = p & 31;
      chain_wait((unsigned*)(ws + 256 + kg * 64), 64u * (st + 1), true, &sDead);
      if (sDead) return;
      // fc GEMM: [128 x 256] @ [256 x 16] over h region of buf[wb]
      {
        const bf16x8* AH = (const bf16x8*)planeH[wb];
        const bf16x8* AL = (const bf16x8*)planeL[wb];
        const bf16x8* BH = (const bf16x8*)sFh;
        const bf16x8* BL = (const bf16x8*)sFl;
        f32x4 z = {0.f, 0.f, 0.f, 0.f};
        f32x4 a0 = z, a1 = z, a2 = z;
        #pragma unroll
        for (int kb = 0; kb < 8; ++kb) {
          int gkb = 16 + kg * 8 + kb;
          bf16x8 ah = AH[(gkb * 8 + w) * 64 + l];
          bf16x8 al = AL[(gkb * 8 + w) * 64 + l];
          bf16x8 bh = BH[kb * 64 + l];
          bf16x8 bl = BL[kb * 64 + l];
          a0 = __builtin_amdgcn_mfma_f32_16x16x32_bf16(ah, bh, a0, 0, 0, 0);
          a1 = __builtin_amdgcn_mfma_f32_16x16x32_bf16(ah, bl, a1, 0, 0, 0);
          a2 = __builtin_amdgcn_mfma_f32_16x16x32_bf16(al, bh, a2, 0, 0, 0);
        }
        f32x4 s = a0 + (a1 + a2);
        int col = cg * 16 + (l & 15), r0 = w * 16 + ((l >> 4) << 2);
        #pragma unroll
        for (int j = 0; j < 4; ++j)
          st_f32(&fp[(size_t)(kg * 128 + r0 + j) * 512 + col], s[j]);
      }
      chain_add(cnt_fc);
      chain_wait(cnt_fc, 128u * (st + 1), false, &sDead);
      if (sDead) return;
      // softmax for batch row s = p
      {
        int s_row = p, c = t;
        float v = fcb_r + ld_f32(&fp[(size_t)(0 * 128 + s_row) * 512 + c])
                        + ld_f32(&fp[(size_t)(1 * 128 + s_row) * 512 + c])
                        + ld_f32(&fp[(size_t)(2 * 128 + s_row) * 512 + c])
                        + ld_f32(&fp[(size_t)(3 * 128 + s_row) * 512 + c]);
        float m = v;
        #pragma unroll
        for (int o = 32; o > 0; o >>= 1) m = fmaxf(m, __shfl_xor(m, o));
        if (l == 0) red[w] = m;
        __syncthreads();
        m = red[0];
        #pragma unroll
        for (int i = 1; i < 8; ++i) m = fmaxf(m, red[i]);
        float e = __expf(v - m);
        float ssum = e;
        #pragma unroll
        for (int o = 32; o > 0; o >>= 1) ssum += __shfl_xor(ssum, o);
        __syncthreads();                 // red reuse
        if (l == 0) red[8 + w] = ssum;
        __syncthreads();
        ssum = (red[8] + red[9]) + (red[10] + red[11]) + (red[12] + red[13]) + (red[14] + red[15]);
        float y = e / ssum;
        out[((size_t)st * 128 + s_row) * 512 + c] = y;
        ybuf[c] = y;
        __syncthreads();
        if (t < 64) {                    // pack y row into buf[wb] x-region
          int kb = t >> 2, seg = t & 3;
          int k = kb * 32 + seg * 8;
          int lane_ = (seg << 4) | (s_row & 15), mt = s_row >> 4;
          int off = ((kb * 8 + mt) * 64 + lane_) * 8;
          unsigned long long h64[2] = {0, 0}, l64[2] = {0, 0};
          #pragma unroll
          for (int j = 0; j < 8; ++j) {
            short hi, lo; split2(ybuf[k + j], hi, lo);
            h64[j >> 2] |= (unsigned long long)(unsigned short)hi << ((j & 3) * 16);
            l64[j >> 2] |= (unsigned long long)(unsigned short)lo << ((j & 3) * 16);
          }
          st_u64(planeH[wb] + off, h64[0]); st_u64(planeH[wb] + off + 4, h64[1]);
          st_u64(planeL[wb] + off, l64[0]); st_u64(planeL[wb] + off + 4, l64[1]);
        }
      }
    }
    step_barrier(cnt_bar, bar_no, &sDead);
    if (sDead) return;
  }
}

extern "C" void kernel_launch(void* const* d_in, const int* in_sizes, int n_in,
                              void* d_out, int out_size, void* d_ws, size_t ws_size,
                              hipStream_t stream) {
  const float* x   = (const float*)d_in[0];
  const float* h0  = (const float*)d_in[1];
  const float* c0  = (const float*)d_in[2];
  const float* eWx = (const float*)d_in[3];
  const float* eWh = (const float*)d_in[4];
  const float* eb  = (const float*)d_in[5];
  const float* dWx = (const float*)d_in[6];
  const float* dWh = (const float*)d_in[7];
  const float* db  = (const float*)d_in[8];
  const float* fcW = (const float*)d_in[9];
  const float* fcb = (const float*)d_in[10];
  float* out = (float*)d_out;

  if (ws_size < (size_t)WS_TOTAL) {
    hipMemsetAsync(d_out, 0xFF, (size_t)out_size * sizeof(float), stream);
    return;
  }
  hipMemsetAsync(d_ws, 0, 4096, stream);   // counters
  hipLaunchKernelGGL(lstm2, dim3(256), dim3(512), 0, stream,
                     x, h0, c0, eWx, eWh, eb, dWx, dWh, db, fcW, fcb, out,
                     (char*)d_ws);
}

// Round 3
// 16871.138 us; speedup vs baseline: 3.8788x; 1.5075x over previous
//
#include <hip/hip_runtime.h>

// ---------------------------------------------------------------------------
// Persistent seq2seq LSTM, v3.
// 256 blocks x 1024 threads (16 waves, 4/SIMD). Block p owns 4 units (16 gate
// cols), full K=1536; gates complete in-block; c stays in registers.
// K is split across wave halves (kh = w>>3); partial gate sums are combined
// via two LDSgate planes.
// Sync: NO central barrier. Monotonic distributed count-waits:
//   - h-lines[4] (by p>>6): 64 adds each per step; "all h of step s done".
//   - y-lines[4] (by p>>5, p<128): 32 adds each per decoder step.
//   - fc-lines[4] (by p>>5): 32 adds each per decoder step.
// Arrivals: s_waitcnt vmcnt(0) + __syncthreads + one atomic add (WT, LLC).
// Waits: t0 polls (agent-scope loads) then acquire-fence (L1/L2 inv).
// Decoder overlap: gate GEMM h-part (kb16..47) gated on h-lines, then x-part
// (kb0..15) gated on y-lines -> softmax latency hides under h-part GEMM.
// ---------------------------------------------------------------------------

#define TS 384

typedef __attribute__((ext_vector_type(8))) short bf16x8;
typedef __attribute__((ext_vector_type(4))) float f32x4;

#define ACT_PLANE 393216u                      // 24576 chunks * 16B
#define WS_ACT 4096u                           // [buf0H, buf0L, buf1H, buf1L]
#define WS_FP  (WS_ACT + 4u*ACT_PLANE)         // fc partials 8*128*512*4 = 2MB
#define WS_TOTAL (WS_FP + 2097152u)

__device__ __forceinline__ unsigned short bf16r(float v) {
  unsigned u = __float_as_uint(v);
  u += 0x7FFFu + ((u >> 16) & 1u);
  return (unsigned short)(u >> 16);
}
__device__ __forceinline__ float bf2f(unsigned short h) {
  return __uint_as_float(((unsigned)h) << 16);
}
__device__ __forceinline__ void split2(float v, short& hi, short& lo) {
  unsigned short h = bf16r(v);
  float r = v - bf2f(h);
  hi = (short)h; lo = (short)bf16r(r);
}
__device__ __forceinline__ float sigm(float v)  { return 1.0f / (1.0f + __expf(-v)); }
__device__ __forceinline__ float tanhfa(float v){ return 1.0f - 2.0f / (__expf(2.0f*v) + 1.0f); }

__device__ __forceinline__ void st_u64(short* p, unsigned long long v) {
  __hip_atomic_store((unsigned long long*)p, v, __ATOMIC_RELAXED, __HIP_MEMORY_SCOPE_AGENT);
}
__device__ __forceinline__ void st_f32(float* p, float v) {
  __hip_atomic_store(p, v, __ATOMIC_RELAXED, __HIP_MEMORY_SCOPE_AGENT);
}
__device__ __forceinline__ float ld_f32(const float* p) {
  return __hip_atomic_load(p, __ATOMIC_RELAXED, __HIP_MEMORY_SCOPE_AGENT);
}
__device__ __forceinline__ unsigned ldc(const unsigned* p) {
  return __hip_atomic_load(p, __ATOMIC_RELAXED, __HIP_MEMORY_SCOPE_AGENT);
}

// element (row,k) -> short offset in a fragment-ordered plane
__device__ __forceinline__ int elem_off(int row, int k) {
  int kb = k >> 5, mt = row >> 4, lane = (((k >> 3) & 3) << 4) | (row & 15);
  return (((kb * 8 + mt) * 64) + lane) * 8 + (k & 7);
}

// ---- sync primitives --------------------------------------------------------
__device__ __forceinline__ void arrive(unsigned* line) {
  asm volatile("s_waitcnt vmcnt(0)" ::: "memory");
  __syncthreads();
  if (threadIdx.x == 0)
    __hip_atomic_fetch_add(line, 1u, __ATOMIC_RELAXED, __HIP_MEMORY_SCOPE_AGENT);
}
__device__ __forceinline__ void wait4(const unsigned* base, unsigned target,
                                      bool fence, int* sDead) {
  if (threadIdx.x == 0) {
    unsigned spins = 0;
    for (;;) {
      unsigned c0 = ldc(base), c1 = ldc(base + 64);
      unsigned c2 = ldc(base + 128), c3 = ldc(base + 192);
      if (c0 >= target && c1 >= target && c2 >= target && c3 >= target) break;
      __builtin_amdgcn_s_sleep(1);
      if (++spins > (1u << 19)) { *sDead = 1; break; }
    }
    if (fence) __builtin_amdgcn_fence(__ATOMIC_ACQUIRE, "agent");
  }
  __syncthreads();
}
__device__ __forceinline__ void wait1(const unsigned* line, unsigned target,
                                      bool fence, int* sDead) {
  if (threadIdx.x == 0) {
    unsigned spins = 0;
    while (ldc(line) < target) {
      __builtin_amdgcn_s_sleep(1);
      if (++spins > (1u << 19)) { *sDead = 1; break; }
    }
    if (fence) __builtin_amdgcn_fence(__ATOMIC_ACQUIRE, "agent");
  }
  __syncthreads();
}

// ---- weight loaders --------------------------------------------------------
__device__ void load_gate_weights(const float* __restrict__ Wx, const float* __restrict__ Wh,
                                  int p, short* sBh, short* sBl) {
  for (int idx = threadIdx.x; idx < 24576; idx += 1024) {
    int j = idx & 7, l = (idx >> 3) & 63, kb = idx >> 9;
    int k = kb * 32 + ((l >> 4) << 3) + j;
    int c = l & 15;
    int gcol = (c >> 2) * 1024 + p * 4 + (c & 3);
    float wv = (k < 512) ? Wx[(size_t)k * 4096 + gcol]
                         : Wh[(size_t)(k - 512) * 4096 + gcol];
    short hi, lo; split2(wv, hi, lo);
    sBh[idx] = hi; sBl[idx] = lo;
  }
}
__device__ void load_fc_weights(const float* __restrict__ fcW, int kg, int cg,
                                short* sFh, short* sFl) {
  for (int idx = threadIdx.x; idx < 4096; idx += 1024) {
    int j = idx & 7, l = (idx >> 3) & 63, kb = idx >> 9;
    int unit = kg * 256 + kb * 32 + ((l >> 4) << 3) + j;
    int col = cg * 16 + (l & 15);
    short hi, lo; split2(fcW[(size_t)unit * 512 + col], hi, lo);
    sFh[idx] = hi; sFl[idx] = lo;
  }
}

// ---- gate GEMM range: kb in [kb0, kb0+2*n2), 3-term split-bf16 -------------
__device__ __forceinline__ void gg_range(
    const bf16x8* __restrict__ AH, const bf16x8* __restrict__ AL,
    const bf16x8* __restrict__ BH, const bf16x8* __restrict__ BL,
    int mt, int l, int kb0, int n2, f32x4* acc)
{
  #pragma unroll 2
  for (int i = 0; i < n2; ++i) {
    int kb = kb0 + i * 2;
    bf16x8 ah0 = AH[(kb * 8 + mt) * 64 + l];
    bf16x8 al0 = AL[(kb * 8 + mt) * 64 + l];
    bf16x8 bh0 = BH[kb * 64 + l];
    bf16x8 bl0 = BL[kb * 64 + l];
    bf16x8 ah1 = AH[((kb + 1) * 8 + mt) * 64 + l];
    bf16x8 al1 = AL[((kb + 1) * 8 + mt) * 64 + l];
    bf16x8 bh1 = BH[(kb + 1) * 64 + l];
    bf16x8 bl1 = BL[(kb + 1) * 64 + l];
    acc[0] = __builtin_amdgcn_mfma_f32_16x16x32_bf16(ah0, bh0, acc[0], 0, 0, 0);
    acc[1] = __builtin_amdgcn_mfma_f32_16x16x32_bf16(ah0, bl0, acc[1], 0, 0, 0);
    acc[2] = __builtin_amdgcn_mfma_f32_16x16x32_bf16(al0, bh0, acc[2], 0, 0, 0);
    acc[3] = __builtin_amdgcn_mfma_f32_16x16x32_bf16(ah1, bh1, acc[3], 0, 0, 0);
    acc[4] = __builtin_amdgcn_mfma_f32_16x16x32_bf16(ah1, bl1, acc[4], 0, 0, 0);
    acc[5] = __builtin_amdgcn_mfma_f32_16x16x32_bf16(al1, bh1, acc[5], 0, 0, 0);
  }
}
__device__ __forceinline__ void gg_finish(f32x4* acc, int kh, int mt, int l,
                                          float* LDSgate) {
  f32x4 s = (acc[0] + acc[3]) + ((acc[1] + acc[4]) + (acc[2] + acc[5]));
  const int col = l & 15, r0 = mt * 16 + ((l >> 4) << 2);
  float* plane = LDSgate + kh * 2176;
  #pragma unroll
  for (int j = 0; j < 4; ++j) plane[(r0 + j) * 17 + col] = s[j];
}

// ---- x conversion into fragment-ordered plane ------------------------------
__device__ __forceinline__ void conv_x(const float* __restrict__ xsrc,
                                       short* dstH, short* dstL, int p, int t) {
  if (t < 32) {
    int g = p * 32 + t;
    int l = g & 63, mt = (g >> 6) & 7, kb = g >> 9;
    int row = mt * 16 + (l & 15), k = kb * 32 + ((l >> 4) << 3);
    const float* xs = xsrc + (size_t)row * 512 + k;
    unsigned long long h64[2] = {0, 0}, l64[2] = {0, 0};
    #pragma unroll
    for (int j = 0; j < 8; ++j) {
      short hi, lo; split2(xs[j], hi, lo);
      h64[j >> 2] |= (unsigned long long)(unsigned short)hi << ((j & 3) * 16);
      l64[j >> 2] |= (unsigned long long)(unsigned short)lo << ((j & 3) * 16);
    }
    int off = g * 8;
    st_u64(dstH + off, h64[0]); st_u64(dstH + off + 4, h64[1]);
    st_u64(dstL + off, l64[0]); st_u64(dstL + off + 4, l64[1]);
  }
}

__global__ void __launch_bounds__(1024, 1)
lstm3(const float* __restrict__ x, const float* __restrict__ h0p,
      const float* __restrict__ c0p, const float* __restrict__ eWx,
      const float* __restrict__ eWh, const float* __restrict__ eb,
      const float* __restrict__ dWx, const float* __restrict__ dWh,
      const float* __restrict__ db, const float* __restrict__ fcW,
      const float* __restrict__ fcb, float* __restrict__ out,
      char* __restrict__ ws)
{
  __shared__ __align__(16) short sBh[24576], sBl[24576];   // 96 KB
  __shared__ __align__(16) short sFh[4096], sFl[4096];     // 16 KB
  __shared__ float LDSgate[2 * 2176];                      // 17.4 KB
  __shared__ unsigned hsplit[512];
  __shared__ float ybuf[512];
  __shared__ float red[16];
  __shared__ int sDead;

  const int p = blockIdx.x, t = threadIdx.x;
  const int w = t >> 6, l = t & 63;
  const int mt = w & 7, kh = w >> 3;
  if (t == 0) sDead = 0;

  unsigned* hln = (unsigned*)ws;                 // 4 lines, 256B apart
  unsigned* yln = (unsigned*)(ws + 1024);
  unsigned* fln = (unsigned*)(ws + 2048);

  float* fp = (float*)(ws + WS_FP);
  short* planeH[2] = { (short*)(ws + WS_ACT),             (short*)(ws + WS_ACT + 2*ACT_PLANE) };
  short* planeL[2] = { (short*)(ws + WS_ACT + ACT_PLANE), (short*)(ws + WS_ACT + 3*ACT_PLANE) };

  const int row_pw = t & 127, u_pw = (t >> 7) & 3;   // pointwise cell (t<512)
  unsigned* my_hline = hln + (p >> 6) * 64;

  // ================= init =================
  load_gate_weights(eWx, eWh, p, sBh, sBl);
  conv_x(x, planeH[0], planeL[0], p, t);
  if (t < 64) {                                  // h0 -> buf0 h-region
    int g = 8192 + p * 64 + t;
    int ll = g & 63, mtt = (g >> 6) & 7, kb = g >> 9;
    int row = mtt * 16 + (ll & 15), k = kb * 32 + ((ll >> 4) << 3);
    const float* hs = h0p + (size_t)row * 1024 + (k - 512);
    unsigned long long h64[2] = {0, 0}, l64[2] = {0, 0};
    #pragma unroll
    for (int j = 0; j < 8; ++j) {
      short hi, lo; split2(hs[j], hi, lo);
      h64[j >> 2] |= (unsigned long long)(unsigned short)hi << ((j & 3) * 16);
      l64[j >> 2] |= (unsigned long long)(unsigned short)lo << ((j & 3) * 16);
    }
    int off = g * 8;
    st_u64(planeH[0] + off, h64[0]); st_u64(planeH[0] + off + 4, h64[1]);
    st_u64(planeL[0] + off, l64[0]); st_u64(planeL[0] + off + 4, l64[1]);
  }
  float creg = 0.f, bq0 = 0.f, bq1 = 0.f, bq2 = 0.f, bq3 = 0.f;
  if (t < 512) {
    creg = c0p[(size_t)row_pw * 1024 + p * 4 + u_pw];
    bq0 = eb[0 * 1024 + p * 4 + u_pw];
    bq1 = eb[1 * 1024 + p * 4 + u_pw];
    bq2 = eb[2 * 1024 + p * 4 + u_pw];
    bq3 = eb[3 * 1024 + p * 4 + u_pw];
  }
  arrive(my_hline);                              // h counts -> 64*1

  // ================= encoder =================
  for (int st = 0; st < TS; ++st) {
    int rb = st & 1, wb = rb ^ 1;
    wait4(hln, 64u * (st + 1), true, &sDead);
    if (sDead) return;
    {
      f32x4 z = {0.f, 0.f, 0.f, 0.f};
      f32x4 acc[6] = {z, z, z, z, z, z};
      gg_range((const bf16x8*)planeH[rb], (const bf16x8*)planeL[rb],
               (const bf16x8*)sBh, (const bf16x8*)sBl, mt, l, kh * 24, 12, acc);
      gg_finish(acc, kh, mt, l, LDSgate);
    }
    __syncthreads();
    if (t < 512) {
      float g0 = LDSgate[row_pw * 17 + 0  + u_pw] + LDSgate[2176 + row_pw * 17 + 0  + u_pw] + bq0;
      float g1 = LDSgate[row_pw * 17 + 4  + u_pw] + LDSgate[2176 + row_pw * 17 + 4  + u_pw] + bq1;
      float g2 = LDSgate[row_pw * 17 + 8  + u_pw] + LDSgate[2176 + row_pw * 17 + 8  + u_pw] + bq2;
      float g3 = LDSgate[row_pw * 17 + 12 + u_pw] + LDSgate[2176 + row_pw * 17 + 12 + u_pw] + bq3;
      creg = sigm(g1) * creg + sigm(g0) * tanhfa(g2);
      float h = sigm(g3) * tanhfa(creg);
      short hi, lo; split2(h, hi, lo);
      hsplit[u_pw * 128 + row_pw] = ((unsigned)(unsigned short)hi << 16) | (unsigned short)lo;
    }
    if (st + 1 < TS) conv_x(x + (size_t)(st + 1) * 128 * 512, planeH[wb], planeL[wb], p, t);
    __syncthreads();
    if (t < 128) {                               // pack+store h slice (4 units)
      int r = t;
      unsigned w0 = hsplit[r], w1 = hsplit[128 + r], w2 = hsplit[256 + r], w3 = hsplit[384 + r];
      unsigned long long hi64 = (unsigned long long)(w0 >> 16)
        | ((unsigned long long)(w1 >> 16) << 16)
        | ((unsigned long long)(w2 >> 16) << 32)
        | ((unsigned long long)(w3 >> 16) << 48);
      unsigned long long lo64 = (unsigned long long)(w0 & 0xFFFFu)
        | ((unsigned long long)(w1 & 0xFFFFu) << 16)
        | ((unsigned long long)(w2 & 0xFFFFu) << 32)
        | ((unsigned long long)(w3 & 0xFFFFu) << 48);
      int off = elem_off(r, 512 + p * 4);
      st_u64(planeH[wb] + off, hi64);
      st_u64(planeL[wb] + off, lo64);
    }
    arrive(my_hline);
  }

  // ================= switch to decoder =================
  // h counts now 64*(TS+1). buf0 holds h_enc (TS even). Zero y0 in buf0.
  load_gate_weights(dWx, dWh, p, sBh, sBl);
  if (p < 128) load_fc_weights(fcW, p >> 5, p & 31, sFh, sFl);
  if (t < 32) {
    int off = (p * 32 + t) * 8;
    st_u64(planeH[0] + off, 0ull); st_u64(planeH[0] + off + 4, 0ull);
    st_u64(planeL[0] + off, 0ull); st_u64(planeL[0] + off + 4, 0ull);
  }
  creg = 0.0f;
  if (t < 512) {
    bq0 = db[0 * 1024 + p * 4 + u_pw];
    bq1 = db[1 * 1024 + p * 4 + u_pw];
    bq2 = db[2 * 1024 + p * 4 + u_pw];
    bq3 = db[3 * 1024 + p * 4 + u_pw];
  }
  float fcb_r = (t < 512) ? fcb[t] : 0.f;
  arrive(my_hline);                              // h counts -> 64*(TS+2)

  // ================= decoder =================
  const unsigned HB = (unsigned)(TS + 2);        // h-count base factor
  for (int st = 0; st < TS; ++st) {
    int rb = st & 1, wb = rb ^ 1;
    f32x4 z = {0.f, 0.f, 0.f, 0.f};
    f32x4 acc[6] = {z, z, z, z, z, z};
    wait4(hln, 64u * (HB + st), true, &sDead);
    if (sDead) return;
    // h-part: kb 16..47
    gg_range((const bf16x8*)planeH[rb], (const bf16x8*)planeL[rb],
             (const bf16x8*)sBh, (const bf16x8*)sBl, mt, l, 16 + kh * 16, 8, acc);
    // y-part gated on softmax(st-1)
    wait4(yln, 32u * st, true, &sDead);
    if (sDead) return;
    gg_range((const bf16x8*)planeH[rb], (const bf16x8*)planeL[rb],
             (const bf16x8*)sBh, (const bf16x8*)sBl, mt, l, kh * 8, 4, acc);
    gg_finish(acc, kh, mt, l, LDSgate);
    __syncthreads();
    if (t < 512) {
      float g0 = LDSgate[row_pw * 17 + 0  + u_pw] + LDSgate[2176 + row_pw * 17 + 0  + u_pw] + bq0;
      float g1 = LDSgate[row_pw * 17 + 4  + u_pw] + LDSgate[2176 + row_pw * 17 + 4  + u_pw] + bq1;
      float g2 = LDSgate[row_pw * 17 + 8  + u_pw] + LDSgate[2176 + row_pw * 17 + 8  + u_pw] + bq2;
      float g3 = LDSgate[row_pw * 17 + 12 + u_pw] + LDSgate[2176 + row_pw * 17 + 12 + u_pw] + bq3;
      creg = sigm(g1) * creg + sigm(g0) * tanhfa(g2);
      float h = sigm(g3) * tanhfa(creg);
      short hi, lo; split2(h, hi, lo);
      hsplit[u_pw * 128 + row_pw] = ((unsigned)(unsigned short)hi << 16) | (unsigned short)lo;
    }
    __syncthreads();
    if (t < 128) {
      int r = t;
      unsigned w0 = hsplit[r], w1 = hsplit[128 + r], w2 = hsplit[256 + r], w3 = hsplit[384 + r];
      unsigned long long hi64 = (unsigned long long)(w0 >> 16)
        | ((unsigned long long)(w1 >> 16) << 16)
        | ((unsigned long long)(w2 >> 16) << 32)
        | ((unsigned long long)(w3 >> 16) << 48);
      unsigned long long lo64 = (unsigned long long)(w0 & 0xFFFFu)
        | ((unsigned long long)(w1 & 0xFFFFu) << 16)
        | ((unsigned long long)(w2 & 0xFFFFu) << 32)
        | ((unsigned long long)(w3 & 0xFFFFu) << 48);
      int off = elem_off(r, 512 + p * 4);
      st_u64(planeH[wb] + off, hi64);
      st_u64(planeL[wb] + off, lo64);
    }
    arrive(my_hline);                            // h counts -> 64*(HB+st+1)
    if (p < 128) {
      const int kg = p >> 5, cg = p & 31;
      wait1(hln + kg * 64, 64u * (HB + st + 1), true, &sDead);
      if (sDead) return;
      // fc GEMM: rows tile mt, K-quarter (kg, kh-half)
      {
        const bf16x8* AH = (const bf16x8*)planeH[wb];
        const bf16x8* AL = (const bf16x8*)planeL[wb];
        const bf16x8* BH = (const bf16x8*)sFh;
        const bf16x8* BL = (const bf16x8*)sFl;
        f32x4 a0 = z, a1 = z, a2 = z;
        #pragma unroll
        for (int kb = 0; kb < 4; ++kb) {
          int gkb = 16 + kg * 8 + kh * 4 + kb;
          bf16x8 ah = AH[(gkb * 8 + mt) * 64 + l];
          bf16x8 al = AL[(gkb * 8 + mt) * 64 + l];
          bf16x8 bh = BH[(kh * 4 + kb) * 64 + l];
          bf16x8 bl = BL[(kh * 4 + kb) * 64 + l];
          a0 = __builtin_amdgcn_mfma_f32_16x16x32_bf16(ah, bh, a0, 0, 0, 0);
          a1 = __builtin_amdgcn_mfma_f32_16x16x32_bf16(ah, bl, a1, 0, 0, 0);
          a2 = __builtin_amdgcn_mfma_f32_16x16x32_bf16(al, bh, a2, 0, 0, 0);
        }
        f32x4 s = a0 + (a1 + a2);
        int slice = kg * 2 + kh;
        int col = cg * 16 + (l & 15), r0 = mt * 16 + ((l >> 4) << 2);
        #pragma unroll
        for (int j = 0; j < 4; ++j)
          st_f32(&fp[(size_t)(slice * 128 + r0 + j) * 512 + col], s[j]);
      }
      arrive(fln + (p >> 5) * 64);
      wait4(fln, 32u * (st + 1), false, &sDead);
      if (sDead) return;
      // softmax for batch row p
      float v = 0.f, e = 0.f, mx;
      if (t < 512) {
        v = fcb_r;
        #pragma unroll
        for (int s8 = 0; s8 < 8; ++s8)
          v += ld_f32(&fp[(size_t)(s8 * 128 + p) * 512 + t]);
        mx = v;
        #pragma unroll
        for (int o = 32; o > 0; o >>= 1) mx = fmaxf(mx, __shfl_xor(mx, o));
        if (l == 0) red[w] = mx;
      }
      __syncthreads();
      if (t < 512) {
        mx = red[0];
        #pragma unroll
        for (int i = 1; i < 8; ++i) mx = fmaxf(mx, red[i]);
        e = __expf(v - mx);
        float ss = e;
        #pragma unroll
        for (int o = 32; o > 0; o >>= 1) ss += __shfl_xor(ss, o);
        if (l == 0) red[8 + w] = ss;
      }
      __syncthreads();
      if (t < 512) {
        float ss = (red[8] + red[9]) + (red[10] + red[11])
                 + (red[12] + red[13]) + (red[14] + red[15]);
        float y = e / ss;
        out[((size_t)st * 128 + p) * 512 + t] = y;
        ybuf[t] = y;
      }
      __syncthreads();
      if (t < 64) {                    // pack y row p into buf[wb] x-region
        int kb = t >> 2, seg = t & 3;
        int k = kb * 32 + seg * 8;
        int lane_ = (seg << 4) | (p & 15), mtt = p >> 4;
        int off = ((kb * 8 + mtt) * 64 + lane_) * 8;
        unsigned long long h64[2] = {0, 0}, l64[2] = {0, 0};
        #pragma unroll
        for (int j = 0; j < 8; ++j) {
          short hi, lo; split2(ybuf[k + j], hi, lo);
          h64[j >> 2] |= (unsigned long long)(unsigned short)hi << ((j & 3) * 16);
          l64[j >> 2] |= (unsigned long long)(unsigned short)lo << ((j & 3) * 16);
        }
        st_u64(planeH[wb] + off, h64[0]); st_u64(planeH[wb] + off + 4, h64[1]);
        st_u64(planeL[wb] + off, l64[0]); st_u64(planeL[wb] + off + 4, l64[1]);
      }
      arrive(yln + (p >> 5) * 64);
    }
  }
}

extern "C" void kernel_launch(void* const* d_in, const int* in_sizes, int n_in,
                              void* d_out, int out_size, void* d_ws, size_t ws_size,
                              hipStream_t stream) {
  const float* x   = (const float*)d_in[0];
  const float* h0  = (const float*)d_in[1];
  const float* c0  = (const float*)d_in[2];
  const float* eWx = (const float*)d_in[3];
  const float* eWh = (const float*)d_in[4];
  const float* eb  = (const float*)d_in[5];
  const float* dWx = (const float*)d_in[6];
  const float* dWh = (const float*)d_in[7];
  const float* db  = (const float*)d_in[8];
  const float* fcW = (const float*)d_in[9];
  const float* fcb = (const float*)d_in[10];
  float* out = (float*)d_out;

  if (ws_size < (size_t)WS_TOTAL) {
    hipMemsetAsync(d_out, 0xFF, (size_t)out_size * sizeof(float), stream);
    return;
  }
  hipMemsetAsync(d_ws, 0, 4096, stream);   // counter lines
  hipLaunchKernelGGL(lstm3, dim3(256), dim3(1024), 0, stream,
                     x, h0, c0, eWx, eWh, eb, dWx, dWh, db, fcW, fcb, out,
                     (char*)d_ws);
}

// Round 4
// 14969.518 us; speedup vs baseline: 4.3716x; 1.1270x over previous
//
#include <hip/hip_runtime.h>

// ---------------------------------------------------------------------------
// Persistent seq2seq LSTM, v4.
// 256 blocks x 1024 threads. Block p owns 16 gate cols (4 units x 4 gates),
// full K=1536; gates complete in-block; c in registers. K split across wave
// halves (kh), partial gate sums combined via two LDSgate planes.
// Memory: x lives in a 4-slot fragment-ordered ring (converted 2 steps ahead
// in encoder; y written by softmax in decoder, 2-slot alternation). h lives
// in 2 alternating fragment-ordered planes. All cross-block payload written
// with agent-scope WT stores; arrivals = vmcnt(0)+add; waits = poll counts.
// Fence discipline: ONE acquire fence (L1+L2 inv) per block per step, at the
// h-wait. All other waits fence-free (freshness guaranteed by count gating +
// no post-fence re-touch of those lines).
// Decoder: gate GEMM h-part (gated on h) -> y-wait -> x-part; fc on blocks
// 128..255, softmax+y-pack on blocks 0..127 (load balance).
// ---------------------------------------------------------------------------

#define TS 384

typedef __attribute__((ext_vector_type(8))) short bf16x8;
typedef __attribute__((ext_vector_type(4))) float f32x4;

// ws layout
#define WS_XR 4096u                      // x ring: 4 slots x (hi 128KB + lo 128KB)
#define XR_SLOT 262144u
#define WS_HP (WS_XR + 4u*XR_SLOT)       // h planes: 2 bufs x (hi 256KB + lo 256KB)
#define HP_BUF 524288u
#define WS_FPN (WS_HP + 2u*HP_BUF)       // fc partials 8*128*512*4 = 2MB
#define WS_TOTAL (WS_FPN + 2097152u)

__device__ __forceinline__ unsigned short bf16r(float v) {
  unsigned u = __float_as_uint(v);
  u += 0x7FFFu + ((u >> 16) & 1u);
  return (unsigned short)(u >> 16);
}
__device__ __forceinline__ float bf2f(unsigned short h) {
  return __uint_as_float(((unsigned)h) << 16);
}
__device__ __forceinline__ void split2(float v, short& hi, short& lo) {
  unsigned short h = bf16r(v);
  float r = v - bf2f(h);
  hi = (short)h; lo = (short)bf16r(r);
}
__device__ __forceinline__ float sigm(float v)  { return 1.0f / (1.0f + __expf(-v)); }
__device__ __forceinline__ float tanhfa(float v){ return 1.0f - 2.0f / (__expf(2.0f*v) + 1.0f); }

__device__ __forceinline__ void st_u64(short* p, unsigned long long v) {
  __hip_atomic_store((unsigned long long*)p, v, __ATOMIC_RELAXED, __HIP_MEMORY_SCOPE_AGENT);
}
__device__ __forceinline__ void st_f32(float* p, float v) {
  __hip_atomic_store(p, v, __ATOMIC_RELAXED, __HIP_MEMORY_SCOPE_AGENT);
}
__device__ __forceinline__ float ld_f32(const float* p) {
  return __hip_atomic_load(p, __ATOMIC_RELAXED, __HIP_MEMORY_SCOPE_AGENT);
}
__device__ __forceinline__ unsigned ldc(const unsigned* p) {
  return __hip_atomic_load(p, __ATOMIC_RELAXED, __HIP_MEMORY_SCOPE_AGENT);
}

// ---- sync primitives --------------------------------------------------------
__device__ __forceinline__ void arrive(unsigned* line) {
  asm volatile("s_waitcnt vmcnt(0)" ::: "memory");
  __syncthreads();
  if (threadIdx.x == 0)
    __hip_atomic_fetch_add(line, 1u, __ATOMIC_RELAXED, __HIP_MEMORY_SCOPE_AGENT);
}
__device__ __forceinline__ void wait4(const unsigned* base, unsigned target,
                                      bool fence, int* sDead) {
  if (threadIdx.x == 0) {
    unsigned spins = 0;
    for (;;) {
      unsigned c0 = ldc(base), c1 = ldc(base + 64);
      unsigned c2 = ldc(base + 128), c3 = ldc(base + 192);
      if (c0 >= target && c1 >= target && c2 >= target && c3 >= target) break;
      __builtin_amdgcn_s_sleep(1);
      if (++spins > (1u << 19)) { *sDead = 1; break; }
    }
    if (fence) __builtin_amdgcn_fence(__ATOMIC_ACQUIRE, "agent");
  }
  __syncthreads();
}
__device__ __forceinline__ void wait1(const unsigned* line, unsigned target,
                                      int* sDead) {
  if (threadIdx.x == 0) {
    unsigned spins = 0;
    while (ldc(line) < target) {
      __builtin_amdgcn_s_sleep(1);
      if (++spins > (1u << 19)) { *sDead = 1; break; }
    }
  }
  __syncthreads();
}

// ---- weight loaders --------------------------------------------------------
__device__ void load_gate_weights(const float* __restrict__ Wx, const float* __restrict__ Wh,
                                  int p, short* sBh, short* sBl) {
  for (int idx = threadIdx.x; idx < 24576; idx += 1024) {
    int j = idx & 7, l = (idx >> 3) & 63, kb = idx >> 9;
    int k = kb * 32 + ((l >> 4) << 3) + j;
    int c = l & 15;
    int gcol = (c >> 2) * 1024 + p * 4 + (c & 3);
    float wv = (k < 512) ? Wx[(size_t)k * 4096 + gcol]
                         : Wh[(size_t)(k - 512) * 4096 + gcol];
    short hi, lo; split2(wv, hi, lo);
    sBh[idx] = hi; sBl[idx] = lo;
  }
}
__device__ void load_fc_weights(const float* __restrict__ fcW, int kg, int cg,
                                short* sFh, short* sFl) {
  for (int idx = threadIdx.x; idx < 4096; idx += 1024) {
    int j = idx & 7, l = (idx >> 3) & 63, kb = idx >> 9;
    int unit = kg * 256 + kb * 32 + ((l >> 4) << 3) + j;
    int col = cg * 16 + (l & 15);
    short hi, lo; split2(fcW[(size_t)unit * 512 + col], hi, lo);
    sFh[idx] = hi; sFl[idx] = lo;
  }
}

// ---- gate GEMM range (A-local kb indexing, B-global kb), split-bf16 --------
__device__ __forceinline__ void gg(const short* AHs, const short* ALs,
    const short* BHs, const short* BLs, int mt, int l,
    int kbA0, int kbB0, int nkb, f32x4* acc)
{
  const bf16x8* AH = (const bf16x8*)AHs;
  const bf16x8* AL = (const bf16x8*)ALs;
  const bf16x8* BH = (const bf16x8*)BHs;
  const bf16x8* BL = (const bf16x8*)BLs;
  #pragma unroll 2
  for (int i = 0; i < nkb; i += 2) {
    int ka = kbA0 + i, kb = kbB0 + i;
    bf16x8 ah0 = AH[(ka * 8 + mt) * 64 + l];
    bf16x8 al0 = AL[(ka * 8 + mt) * 64 + l];
    bf16x8 bh0 = BH[kb * 64 + l];
    bf16x8 bl0 = BL[kb * 64 + l];
    bf16x8 ah1 = AH[((ka + 1) * 8 + mt) * 64 + l];
    bf16x8 al1 = AL[((ka + 1) * 8 + mt) * 64 + l];
    bf16x8 bh1 = BH[(kb + 1) * 64 + l];
    bf16x8 bl1 = BL[(kb + 1) * 64 + l];
    acc[0] = __builtin_amdgcn_mfma_f32_16x16x32_bf16(ah0, bh0, acc[0], 0, 0, 0);
    acc[1] = __builtin_amdgcn_mfma_f32_16x16x32_bf16(ah0, bl0, acc[1], 0, 0, 0);
    acc[2] = __builtin_amdgcn_mfma_f32_16x16x32_bf16(al0, bh0, acc[2], 0, 0, 0);
    acc[3] = __builtin_amdgcn_mfma_f32_16x16x32_bf16(ah1, bh1, acc[3], 0, 0, 0);
    acc[4] = __builtin_amdgcn_mfma_f32_16x16x32_bf16(ah1, bl1, acc[4], 0, 0, 0);
    acc[5] = __builtin_amdgcn_mfma_f32_16x16x32_bf16(al1, bh1, acc[5], 0, 0, 0);
  }
}
__device__ __forceinline__ void gg_finish(f32x4* acc, int kh, int mt, int l,
                                          float* LDSgate) {
  f32x4 s = (acc[0] + acc[3]) + ((acc[1] + acc[4]) + (acc[2] + acc[5]));
  const int col = l & 15, r0 = mt * 16 + ((l >> 4) << 2);
  float* plane = LDSgate + kh * 2176;
  #pragma unroll
  for (int j = 0; j < 4; ++j) plane[(r0 + j) * 17 + col] = s[j];
}

// ---- x conversion into fragment-ordered x-ring slot ------------------------
__device__ __forceinline__ void conv_x(const float* __restrict__ xsrc,
                                       short* dstH, short* dstL, int p, int t) {
  if (t < 32) {
    int g = p * 32 + t;                       // 0..8191
    int l = g & 63, mt = (g >> 6) & 7, kb = g >> 9;
    int row = mt * 16 + (l & 15), k = kb * 32 + ((l >> 4) << 3);
    const float* xs = xsrc + (size_t)row * 512 + k;
    unsigned long long h64[2] = {0, 0}, l64[2] = {0, 0};
    #pragma unroll
    for (int j = 0; j < 8; ++j) {
      short hi, lo; split2(xs[j], hi, lo);
      h64[j >> 2] |= (unsigned long long)(unsigned short)hi << ((j & 3) * 16);
      l64[j >> 2] |= (unsigned long long)(unsigned short)lo << ((j & 3) * 16);
    }
    int off = g * 8;
    st_u64(dstH + off, h64[0]); st_u64(dstH + off + 4, h64[1]);
    st_u64(dstL + off, l64[0]); st_u64(dstL + off + 4, l64[1]);
  }
}

__global__ void __launch_bounds__(1024, 1)
lstm4(const float* __restrict__ x, const float* __restrict__ h0p,
      const float* __restrict__ c0p, const float* __restrict__ eWx,
      const float* __restrict__ eWh, const float* __restrict__ eb,
      const float* __restrict__ dWx, const float* __restrict__ dWh,
      const float* __restrict__ db, const float* __restrict__ fcW,
      const float* __restrict__ fcb, float* __restrict__ out,
      char* __restrict__ ws)
{
  __shared__ __align__(16) short sBh[24576], sBl[24576];   // 96 KB
  __shared__ __align__(16) short sFh[4096], sFl[4096];     // 16 KB
  __shared__ float LDSgate[2 * 2176];                      // 17.4 KB
  __shared__ unsigned hsplit[512];
  __shared__ float ybuf[512];
  __shared__ float red[16];
  __shared__ int sDead;

  const int p = blockIdx.x, t = threadIdx.x;
  const int w = t >> 6, l = t & 63;
  const int mt = w & 7, kh = w >> 3;
  if (t == 0) sDead = 0;

  unsigned* hln = (unsigned*)ws;
  unsigned* yln = (unsigned*)(ws + 1024);
  unsigned* fln = (unsigned*)(ws + 2048);
  unsigned* my_hline = hln + (p >> 6) * 64;

  short* xrH[4]; short* xrL[4];
  #pragma unroll
  for (int s4 = 0; s4 < 4; ++s4) {
    xrH[s4] = (short*)(ws + WS_XR + s4 * XR_SLOT);
    xrL[s4] = (short*)(ws + WS_XR + s4 * XR_SLOT + 131072u);
  }
  short* hpH[2]; short* hpL[2];
  #pragma unroll
  for (int b2 = 0; b2 < 2; ++b2) {
    hpH[b2] = (short*)(ws + WS_HP + b2 * HP_BUF);
    hpL[b2] = (short*)(ws + WS_HP + b2 * HP_BUF + 262144u);
  }
  float* fp = (float*)(ws + WS_FPN);

  const int row_pw = t & 127, u_pw = (t >> 7) & 3;

  // ================= init =================
  load_gate_weights(eWx, eWh, p, sBh, sBl);
  conv_x(x, xrH[0], xrL[0], p, t);                       // x(0)
  conv_x(x + 65536, xrH[1], xrL[1], p, t);               // x(1)
  if (t < 64) {                                          // h0 -> hp[0]
    int hg = p * 64 + t;
    int ll = hg & 63, mtt = (hg >> 6) & 7, hk = hg >> 9;
    int row = mtt * 16 + (ll & 15), k = hk * 32 + ((ll >> 4) << 3);
    const float* hs = h0p + (size_t)row * 1024 + k;
    unsigned long long h64[2] = {0, 0}, l64[2] = {0, 0};
    #pragma unroll
    for (int j = 0; j < 8; ++j) {
      short hi, lo; split2(hs[j], hi, lo);
      h64[j >> 2] |= (unsigned long long)(unsigned short)hi << ((j & 3) * 16);
      l64[j >> 2] |= (unsigned long long)(unsigned short)lo << ((j & 3) * 16);
    }
    int off = hg * 8;
    st_u64(hpH[0] + off, h64[0]); st_u64(hpH[0] + off + 4, h64[1]);
    st_u64(hpL[0] + off, l64[0]); st_u64(hpL[0] + off + 4, l64[1]);
  }
  float creg = 0.f, bq0 = 0.f, bq1 = 0.f, bq2 = 0.f, bq3 = 0.f;
  if (t < 512) {
    creg = c0p[(size_t)row_pw * 1024 + p * 4 + u_pw];
    bq0 = eb[0 * 1024 + p * 4 + u_pw];
    bq1 = eb[1 * 1024 + p * 4 + u_pw];
    bq2 = eb[2 * 1024 + p * 4 + u_pw];
    bq3 = eb[3 * 1024 + p * 4 + u_pw];
  }
  arrive(my_hline);                                      // -> 64*1
  wait4(hln, 64u, true, &sDead);
  if (sDead) return;

  // ================= encoder =================
  for (int st = 0; st < TS; ++st) {
    int rb = st & 1, wb = rb ^ 1, xs = st & 3;
    f32x4 z = {0.f, 0.f, 0.f, 0.f};
    f32x4 acc[6] = {z, z, z, z, z, z};
    // x-part BEFORE the wait (x(st) readiness implied by step st-1's count)
    gg(xrH[xs], xrL[xs], sBh, sBl, mt, l, kh * 8, kh * 8, 8, acc);
    wait4(hln, 64u * (st + 1), true, &sDead);            // the one fence/step
    if (sDead) return;
    gg(hpH[rb], hpL[rb], sBh, sBl, mt, l, kh * 16, 16 + kh * 16, 16, acc);
    gg_finish(acc, kh, mt, l, LDSgate);
    __syncthreads();
    if (t < 512) {
      float g0 = LDSgate[row_pw * 17 + 0  + u_pw] + LDSgate[2176 + row_pw * 17 + 0  + u_pw] + bq0;
      float g1 = LDSgate[row_pw * 17 + 4  + u_pw] + LDSgate[2176 + row_pw * 17 + 4  + u_pw] + bq1;
      float g2 = LDSgate[row_pw * 17 + 8  + u_pw] + LDSgate[2176 + row_pw * 17 + 8  + u_pw] + bq2;
      float g3 = LDSgate[row_pw * 17 + 12 + u_pw] + LDSgate[2176 + row_pw * 17 + 12 + u_pw] + bq3;
      creg = sigm(g1) * creg + sigm(g0) * tanhfa(g2);
      float h = sigm(g3) * tanhfa(creg);
      short hi, lo; split2(h, hi, lo);
      hsplit[u_pw * 128 + row_pw] = ((unsigned)(unsigned short)hi << 16) | (unsigned short)lo;
    }
    if (st + 2 < TS)
      conv_x(x + (size_t)(st + 2) * 65536, xrH[(st + 2) & 3], xrL[(st + 2) & 3], p, t);
    __syncthreads();
    if (t < 128) {                                       // pack h slice (4 units)
      int r = t;
      unsigned w0 = hsplit[r], w1 = hsplit[128 + r], w2 = hsplit[256 + r], w3 = hsplit[384 + r];
      unsigned long long hi64 = (unsigned long long)(w0 >> 16)
        | ((unsigned long long)(w1 >> 16) << 16)
        | ((unsigned long long)(w2 >> 16) << 32)
        | ((unsigned long long)(w3 >> 16) << 48);
      unsigned long long lo64 = (unsigned long long)(w0 & 0xFFFFu)
        | ((unsigned long long)(w1 & 0xFFFFu) << 16)
        | ((unsigned long long)(w2 & 0xFFFFu) << 32)
        | ((unsigned long long)(w3 & 0xFFFFu) << 48);
      int hk = p >> 3, mtt = r >> 4;
      int lane_ = (((p >> 1) & 3) << 4) | (r & 15);
      int off = ((hk * 8 + mtt) * 64 + lane_) * 8 + (p & 1) * 4;
      st_u64(hpH[wb] + off, hi64);
      st_u64(hpL[wb] + off, lo64);
    }
    arrive(my_hline);
  }

  // ================= switch to decoder =================
  load_gate_weights(dWx, dWh, p, sBh, sBl);
  if (p >= 128) load_fc_weights(fcW, (p - 128) >> 5, (p - 128) & 31, sFh, sFl);
  if (t < 32) {                                          // zero y0 (slot 0)
    int off = (p * 32 + t) * 8;
    st_u64(xrH[0] + off, 0ull); st_u64(xrH[0] + off + 4, 0ull);
    st_u64(xrL[0] + off, 0ull); st_u64(xrL[0] + off + 4, 0ull);
  }
  creg = 0.0f;
  if (t < 512) {
    bq0 = db[0 * 1024 + p * 4 + u_pw];
    bq1 = db[1 * 1024 + p * 4 + u_pw];
    bq2 = db[2 * 1024 + p * 4 + u_pw];
    bq3 = db[3 * 1024 + p * 4 + u_pw];
  }
  float fcb_r = (t < 512) ? fcb[t] : 0.f;
  arrive(my_hline);                                      // -> 64*(TS+2)

  // ================= decoder =================
  const unsigned HB = (unsigned)(TS + 2);
  for (int st = 0; st < TS; ++st) {
    int rb = st & 1, wb = rb ^ 1;
    int ys = st & 1, yw = ys ^ 1;
    f32x4 z = {0.f, 0.f, 0.f, 0.f};
    f32x4 acc[6] = {z, z, z, z, z, z};
    wait4(hln, 64u * (HB + st), true, &sDead);           // the one fence/step
    if (sDead) return;
    gg(hpH[rb], hpL[rb], sBh, sBl, mt, l, kh * 16, 16 + kh * 16, 16, acc);
    wait4(yln, 32u * st, false, &sDead);                 // y(st-1)
    if (sDead) return;
    gg(xrH[ys], xrL[ys], sBh, sBl, mt, l, kh * 8, kh * 8, 8, acc);
    gg_finish(acc, kh, mt, l, LDSgate);
    __syncthreads();
    if (t < 512) {
      float g0 = LDSgate[row_pw * 17 + 0  + u_pw] + LDSgate[2176 + row_pw * 17 + 0  + u_pw] + bq0;
      float g1 = LDSgate[row_pw * 17 + 4  + u_pw] + LDSgate[2176 + row_pw * 17 + 4  + u_pw] + bq1;
      float g2 = LDSgate[row_pw * 17 + 8  + u_pw] + LDSgate[2176 + row_pw * 17 + 8  + u_pw] + bq2;
      float g3 = LDSgate[row_pw * 17 + 12 + u_pw] + LDSgate[2176 + row_pw * 17 + 12 + u_pw] + bq3;
      creg = sigm(g1) * creg + sigm(g0) * tanhfa(g2);
      float h = sigm(g3) * tanhfa(creg);
      short hi, lo; split2(h, hi, lo);
      hsplit[u_pw * 128 + row_pw] = ((unsigned)(unsigned short)hi << 16) | (unsigned short)lo;
    }
    __syncthreads();
    if (t < 128) {
      int r = t;
      unsigned w0 = hsplit[r], w1 = hsplit[128 + r], w2 = hsplit[256 + r], w3 = hsplit[384 + r];
      unsigned long long hi64 = (unsigned long long)(w0 >> 16)
        | ((unsigned long long)(w1 >> 16) << 16)
        | ((unsigned long long)(w2 >> 16) << 32)
        | ((unsigned long long)(w3 >> 16) << 48);
      unsigned long long lo64 = (unsigned long long)(w0 & 0xFFFFu)
        | ((unsigned long long)(w1 & 0xFFFFu) << 16)
        | ((unsigned long long)(w2 & 0xFFFFu) << 32)
        | ((unsigned long long)(w3 & 0xFFFFu) << 48);
      int hk = p >> 3, mtt = r >> 4;
      int lane_ = (((p >> 1) & 3) << 4) | (r & 15);
      int off = ((hk * 8 + mtt) * 64 + lane_) * 8 + (p & 1) * 4;
      st_u64(hpH[wb] + off, hi64);
      st_u64(hpL[wb] + off, lo64);
    }
    arrive(my_hline);                                    // h(st) -> 64*(HB+st+1)

    if (p >= 128) {
      // ---- fc GEMM on blocks 128..255 ----
      const int f = p - 128, kg = f >> 5, cg = f & 31;
      wait1(hln + kg * 64, 64u * (HB + st + 1), &sDead); // h units kg*256.. ready
      if (sDead) return;
      {
        const bf16x8* AH = (const bf16x8*)hpH[wb];
        const bf16x8* AL = (const bf16x8*)hpL[wb];
        const bf16x8* BH = (const bf16x8*)sFh;
        const bf16x8* BL = (const bf16x8*)sFl;
        f32x4 a0 = z, a1 = z, a2 = z;
        #pragma unroll
        for (int kb = 0; kb < 4; ++kb) {
          int hk = kg * 8 + kh * 4 + kb;
          bf16x8 ah = AH[(hk * 8 + mt) * 64 + l];
          bf16x8 al = AL[(hk * 8 + mt) * 64 + l];
          bf16x8 bh = BH[(kh * 4 + kb) * 64 + l];
          bf16x8 bl = BL[(kh * 4 + kb) * 64 + l];
          a0 = __builtin_amdgcn_mfma_f32_16x16x32_bf16(ah, bh, a0, 0, 0, 0);
          a1 = __builtin_amdgcn_mfma_f32_16x16x32_bf16(ah, bl, a1, 0, 0, 0);
          a2 = __builtin_amdgcn_mfma_f32_16x16x32_bf16(al, bh, a2, 0, 0, 0);
        }
        f32x4 s = a0 + (a1 + a2);
        int slice = kg * 2 + kh;
        int col = cg * 16 + (l & 15), r0 = mt * 16 + ((l >> 4) << 2);
        #pragma unroll
        for (int j = 0; j < 4; ++j)
          st_f32(&fp[(size_t)(slice * 128 + r0 + j) * 512 + col], s[j]);
      }
      arrive(fln + (f >> 5) * 64);
    } else {
      // ---- softmax + y-pack on blocks 0..127 ----
      wait4(fln, 32u * (st + 1), false, &sDead);
      if (sDead) return;
      float v = 0.f, e = 0.f, mx;
      if (t < 512) {
        v = fcb_r;
        #pragma unroll
        for (int s8 = 0; s8 < 8; ++s8)
          v += ld_f32(&fp[(size_t)(s8 * 128 + p) * 512 + t]);
        mx = v;
        #pragma unroll
        for (int o = 32; o > 0; o >>= 1) mx = fmaxf(mx, __shfl_xor(mx, o));
        if (l == 0) red[w] = mx;
      }
      __syncthreads();
      if (t < 512) {
        mx = red[0];
        #pragma unroll
        for (int i = 1; i < 8; ++i) mx = fmaxf(mx, red[i]);
        e = __expf(v - mx);
        float ss = e;
        #pragma unroll
        for (int o = 32; o > 0; o >>= 1) ss += __shfl_xor(ss, o);
        if (l == 0) red[8 + w] = ss;
      }
      __syncthreads();
      if (t < 512) {
        float ss = (red[8] + red[9]) + (red[10] + red[11])
                 + (red[12] + red[13]) + (red[14] + red[15]);
        float y = e / ss;
        out[((size_t)st * 128 + p) * 512 + t] = y;
        ybuf[t] = y;
      }
      __syncthreads();
      if (t < 64) {                                      // pack y row p
        int kb = t >> 2, seg = t & 3;
        int k = kb * 32 + seg * 8;
        int lane_ = (seg << 4) | (p & 15), mtt = p >> 4;
        int off = ((kb * 8 + mtt) * 64 + lane_) * 8;
        unsigned long long h64[2] = {0, 0}, l64[2] = {0, 0};
        #pragma unroll
        for (int j = 0; j < 8; ++j) {
          short hi, lo; split2(ybuf[k + j], hi, lo);
          h64[j >> 2] |= (unsigned long long)(unsigned short)hi << ((j & 3) * 16);
          l64[j >> 2] |= (unsigned long long)(unsigned short)lo << ((j & 3) * 16);
        }
        st_u64(xrH[yw] + off, h64[0]); st_u64(xrH[yw] + off + 4, h64[1]);
        st_u64(xrL[yw] + off, l64[0]); st_u64(xrL[yw] + off + 4, l64[1]);
      }
      arrive(yln + (p >> 5) * 64);
    }
  }
}

extern "C" void kernel_launch(void* const* d_in, const int* in_sizes, int n_in,
                              void* d_out, int out_size, void* d_ws, size_t ws_size,
                              hipStream_t stream) {
  const float* x   = (const float*)d_in[0];
  const float* h0  = (const float*)d_in[1];
  const float* c0  = (const float*)d_in[2];
  const float* eWx = (const float*)d_in[3];
  const float* eWh = (const float*)d_in[4];
  const float* eb  = (const float*)d_in[5];
  const float* dWx = (const float*)d_in[6];
  const float* dWh = (const float*)d_in[7];
  const float* db  = (const float*)d_in[8];
  const float* fcW = (const float*)d_in[9];
  const float* fcb = (const float*)d_in[10];
  float* out = (float*)d_out;

  if (ws_size < (size_t)WS_TOTAL) {
    hipMemsetAsync(d_out, 0xFF, (size_t)out_size * sizeof(float), stream);
    return;
  }
  hipMemsetAsync(d_ws, 0, 4096, stream);   // counter lines
  hipLaunchKernelGGL(lstm4, dim3(256), dim3(1024), 0, stream,
                     x, h0, c0, eWx, eWh, eb, dWx, dWh, db, fcW, fcb, out,
                     (char*)d_ws);
}